// Round 1
// baseline (3621.005 us; speedup 1.0000x reference)
//
#include <hip/hip_runtime.h>
#include <hip/hip_bf16.h>
#include <stdint.h>

#define LATENT 256
#define HIDDEN 1024
#define GOUT 512
#define NB 32
#define TT 512
#define G3 1536

typedef float f32x4 __attribute__((ext_vector_type(4)));
typedef short s16x8 __attribute__((ext_vector_type(8)));
typedef uint32_t u32;
typedef unsigned long long u64;

#define GLP(p) ((const __attribute__((address_space(1))) u32*)(p))
#define LLP(p) ((__attribute__((address_space(3))) u32*)(p))

__device__ __forceinline__ short f2bf(float f) {
  u32 u = __builtin_bit_cast(u32, f);
  u32 r = (u + 0x7FFFu + ((u >> 16) & 1u)) >> 16;
  return (short)r;
}
__device__ __forceinline__ float bf2f(short s) {
  u32 u = ((u32)(unsigned short)s) << 16;
  return __builtin_bit_cast(float, u);
}
__device__ __forceinline__ u32 pk2(float a, float b) {
  return (u32)(unsigned short)f2bf(a) | ((u32)(unsigned short)f2bf(b) << 16);
}
__device__ __forceinline__ s16x8 f2bf8(float4 a, float4 b) {
  s16x8 r;
  r[0] = f2bf(a.x); r[1] = f2bf(a.y); r[2] = f2bf(a.z); r[3] = f2bf(a.w);
  r[4] = f2bf(b.x); r[5] = f2bf(b.y); r[6] = f2bf(b.z); r[7] = f2bf(b.w);
  return r;
}
__device__ __forceinline__ float ldgx(const float* p) { return *p; }
__device__ __forceinline__ float ldgx(const short* p) { return bf2f(*p); }
__device__ __forceinline__ u64 ald(const u64* p) {
  return __hip_atomic_load(p, __ATOMIC_RELAXED, __HIP_MEMORY_SCOPE_AGENT);
}

// ---------------- fc + relu ----------------
__global__ __launch_bounds__(256) void fc_kernel(const float* __restrict__ z,
                                                 const float* __restrict__ fc_w,
                                                 const float* __restrict__ fc_b,
                                                 float* __restrict__ hfc) {
  __shared__ float zs[LATENT];
  int tid = threadIdx.x;
  int gid = blockIdx.x * 256 + tid;
  int b = gid >> 10, j = gid & 1023;
  zs[tid] = z[b * LATENT + tid];
  __syncthreads();
  const float4* wr = (const float4*)(fc_w + (size_t)j * LATENT);
  float s = 0.f;
#pragma unroll
  for (int k = 0; k < LATENT / 4; ++k) {
    float4 wv = wr[k];
    float4 zv = *(const float4*)&zs[k * 4];
    s += wv.x * zv.x + wv.y * zv.y + wv.z * zv.z + wv.w * zv.w;
  }
  s += fc_b[j];
  hfc[gid] = fmaxf(s, 0.f);
}

// ------------- x0[t][b][k] = bf16(hfc[b][k] + chord[b][t][k]/100) -------------
__global__ __launch_bounds__(256) void x0_kernel(const float* __restrict__ hfc,
                                                 const float* __restrict__ chord,
                                                 short* __restrict__ x0) {
  int r = blockIdx.x;          // r = t*32 + b
  int b = r & 31, t = r >> 5;
  int k = threadIdx.x * 4;
  float4 c = *(const float4*)(chord + ((size_t)b * TT + t) * HIDDEN + k);
  float4 h = *(const float4*)(hfc + (size_t)b * HIDDEN + k);
  u32 p0 = pk2(h.x + c.x * 0.01f, h.y + c.y * 0.01f);
  u32 p1 = pk2(h.z + c.z * 0.01f, h.w + c.w * 0.01f);
  uint2 pv; pv.x = p0; pv.y = p1;
  *(uint2*)(x0 + (size_t)r * HIDDEN + k) = pv;
}

// ---------------- fp32 -> bf16 weight convert ----------------
__global__ __launch_bounds__(256) void cvt_kernel(const float* __restrict__ src,
                                                  short* __restrict__ dst, int n4) {
  int i = blockIdx.x * 256 + threadIdx.x;
  if (i < n4) {
    float4 v = ((const float4*)src)[i];
    uint2 pv; pv.x = pk2(v.x, v.y); pv.y = pk2(v.z, v.w);
    ((uint2*)dst)[i] = pv;
  }
}

// ---------------- GEMM: C[M][N] = A[M][K](bf16) @ Bw[N][K]^T(bf16) ----------------
template <typename OutT>
__global__ __launch_bounds__(256) void gemm_bt(const short* __restrict__ A,
                                               const short* __restrict__ Bw,
                                               OutT* __restrict__ C, int M, int N, int K) {
  __shared__ short As[128 * 32];
  __shared__ short Bs[128 * 32];
  const int tid = threadIdx.x;
  const int lane = tid & 63, wave = tid >> 6;
  const int l15 = lane & 15, quad = lane >> 4;
  const int n0 = blockIdx.x * 128, m0 = blockIdx.y * 128;
  const int wm = (wave >> 1) * 64, wn = (wave & 1) * 64;
  f32x4 acc[4][4] = {};
  for (int k0 = 0; k0 < K; k0 += 32) {
#pragma unroll
    for (int c = 0; c < 2; ++c) {
      int idx = c * 256 + tid;
      int row = idx >> 2, cs = (idx & 3) * 8;
      const u32* ga = (const u32*)(A + (size_t)(m0 + row) * K + k0 + cs);
      const u32* gb = (const u32*)(Bw + (size_t)(n0 + row) * K + k0 + cs);
      u32* sa = (u32*)As + (size_t)(c * 256 + wave * 64) * 4;
      u32* sb = (u32*)Bs + (size_t)(c * 256 + wave * 64) * 4;
      __builtin_amdgcn_global_load_lds(GLP(ga), LLP(sa), 16, 0, 0);
      __builtin_amdgcn_global_load_lds(GLP(gb), LLP(sb), 16, 0, 0);
    }
    __syncthreads();
    s16x8 af[4], bfr[4];
#pragma unroll
    for (int i = 0; i < 4; ++i)
      af[i] = *(const s16x8*)(As + (wm + i * 16 + l15) * 32 + quad * 8);
#pragma unroll
    for (int j = 0; j < 4; ++j)
      bfr[j] = *(const s16x8*)(Bs + (wn + j * 16 + l15) * 32 + quad * 8);
#pragma unroll
    for (int i = 0; i < 4; ++i)
#pragma unroll
      for (int j = 0; j < 4; ++j)
        acc[i][j] = __builtin_amdgcn_mfma_f32_16x16x32_bf16(af[i], bfr[j], acc[i][j], 0, 0, 0);
    __syncthreads();
  }
#pragma unroll
  for (int i = 0; i < 4; ++i)
#pragma unroll
    for (int j = 0; j < 4; ++j)
#pragma unroll
      for (int r = 0; r < 4; ++r) {
        int m = m0 + wm + i * 16 + quad * 4 + r;
        int n = n0 + wn + j * 16 + l15;
        float v = acc[i][j][r];
        if constexpr (__is_same(OutT, float)) C[(size_t)m * N + n] = v;
        else C[(size_t)m * N + n] = f2bf(v);
      }
}

// ======================= fused 3-layer pipelined GRU (v4) =======================
// Layers are causally skewed by 1 step: layer l+1 step t needs only h_l(t).
// Run all 3 layers concurrently; total ~514 slots instead of 3*512.
//
// Grid: 96 WGs x 1024 thr = 3 layers x 2 groups(16 batches) x 16 unit-WGs(32 units).
// 1 WG/CU, 96 <= 256 CUs -> all resident (required: inter-WG spin protocol).
// Waves 0-5:  hh gates (w_hh frags persistent, 64 VGPR), [16,512]x[512,96]/WG.
// Waves 6-11: ih gates (w_ih frags) for layers 1/2: gx on the fly from the
//             broadcast bf16 h of the layer below (kills 2 big GEMMs + x1 buf).
//             Layer 0 reads precomputed gx0 (big GEMM, K=1024 too big for frags).
// Waves 12-15: combine, 2 (batch,unit) pairs/thread; transcendentals off MFMA waves.
//
// Handoff: tagged u64 words (tag(hi32) = t+1, payload 2 bf16), relaxed agent
// atomics, depth-4 ring per (layer,group). Safety:
//  - backpressure: before overwriting ring slot t&3 (holds h(t-4), which is
//    layer l+1's x input), poll that layer l+1 finished step t-4 (tag >= t-3 in
//    one word per consumer-WG slice). Own-layer skew is <=1 by construction.
//  - tags cleared every launch (per-layer buffers would otherwise see
//    tag-equal stale words from the previous benchmark iteration).
// LDS A-tile swizzle: addr(r,c) = r*256 + (c ^ (r<<2)) -> <=2-way on b128 reads
// (free, m136) and uint4-contiguous staging writes.

struct GruP {
  const float* w_hh[3];
  const float* w_ih[3];   // [0] unused (gx0 precomputed)
  const float* b_ih[3];
  const float* b_hh[3];
};

#define SLOT_WORDS 4096          // 16 batches * 256 u64 words
#define HB_WORDS  (4 * SLOT_WORDS)  // depth-4 ring per (layer,group)

__global__ __launch_bounds__(256) void clr_kernel(u64* __restrict__ p) {
  p[(size_t)blockIdx.x * 256 + threadIdx.x] = 0ull;
}

template <typename GxT>
__global__ __launch_bounds__(1024) void gru3(GruP P,
                                             const GxT* __restrict__ gx0,    // [T][32][1536]
                                             u64* __restrict__ hbc,
                                             const int* __restrict__ seq,
                                             float* __restrict__ out) {     // [32][T][512]
  const int bid = blockIdx.x;
  const int layer = bid >> 5;               // 0..2
  const int g = bid & 1;                    // group (batches g*16..g*16+15)
  const int wg = (bid >> 1) & 15;           // unit-WG
  const int u0 = wg * 32;
  const int tid = threadIdx.x;
  const int lane = tid & 63, wave = tid >> 6;
  const int l15 = lane & 15, quad = lane >> 4;

  __shared__ u32 h_lds[16 * 256];           // own-layer h(t-1), swizzled
  __shared__ u32 x_lds[16 * 256];           // prev-layer h(t) = x_t, swizzled
  __shared__ float gh_c[3 * 512];           // [gate][batch16][unit32]
  __shared__ float gx_c[3 * 512];

  u64* hb_own = hbc + (size_t)(layer * 2 + g) * HB_WORDS;
  const u64* hb_prev = (layer > 0) ? hbc + (size_t)((layer - 1) * 2 + g) * HB_WORDS : hbc;
  const u64* hb_next = (layer < 2) ? hbc + (size_t)((layer + 1) * 2 + g) * HB_WORDS : hbc;

  const bool is_hh = (wave < 6);
  const bool do_ih = (wave >= 6 && wave < 12 && layer > 0);
  const bool is_c  = (wave >= 12);

  // --- persistent weight fragments for gate waves ---
  int gate = 0, half = 0;
  s16x8 wfrag[16];
  if (is_hh || do_ih) {
    const int wv = is_hh ? wave : wave - 6;
    gate = wv >> 1; half = wv & 1;
    const float* W = is_hh ? P.w_hh[layer] : P.w_ih[layer];
    const int col = gate * 512 + u0 + half * 16 + l15;
#pragma unroll
    for (int kb = 0; kb < 16; ++kb) {
      const float* p = W + (size_t)col * 512 + kb * 32 + quad * 8;
      wfrag[kb] = f2bf8(*(const float4*)p, *(const float4*)(p + 4));
    }
  }

  // --- combine setup: 2 (batch,unit) pairs per thread ---
  const int ci0 = tid - 768;
  float bih[2][3], bhh[2][3], pgx[2][3], hprev[2];
  int slen[2];
  hprev[0] = hprev[1] = 0.f; slen[0] = slen[1] = 0;
#pragma unroll
  for (int p = 0; p < 2; ++p)
#pragma unroll
    for (int gs = 0; gs < 3; ++gs) { bih[p][gs] = 0.f; bhh[p][gs] = 0.f; pgx[p][gs] = 0.f; }
  if (is_c) {
#pragma unroll
    for (int p = 0; p < 2; ++p) {
      const int ci = ci0 + p * 256;
      const int cu = ci & 31, cb = ci >> 5;
      const int u = u0 + cu, gb = g * 16 + cb;
#pragma unroll
      for (int gs = 0; gs < 3; ++gs) {
        bih[p][gs] = P.b_ih[layer][gs * 512 + u];
        bhh[p][gs] = P.b_hh[layer][gs * 512 + u];
      }
      slen[p] = seq[gb];
      if (layer == 0) {
#pragma unroll
        for (int gs = 0; gs < 3; ++gs)
          pgx[p][gs] = ldgx(&gx0[(size_t)gb * G3 + gs * 512 + u]);
      }
    }
  }

  // --- poll/stage mapping: thread owns words [4*tid, 4*tid+4) ---
  const int w0 = tid * 4;
  const int srow = w0 >> 8;                  // == wave
  const int saddr = srow * 256 + ((w0 & 255) ^ (srow << 2));

  for (int t = 0; t < TT; ++t) {
    // ---- issue all global poll loads first (parallel latency) ----
    const bool chk = (layer < 2 && t >= 4 && tid < 16);
    const u64* cw = hb_next + (size_t)(t & 3) * SLOT_WORDS + tid * 16;
    u64 cv = 0;
    if (chk) cv = ald(cw);
    const u64* hsrc = hb_own + (size_t)((t - 1) & 3) * SLOT_WORDS + w0;
    u64 hv0 = 0, hv1 = 0, hv2 = 0, hv3 = 0;
    if (t > 0) { hv0 = ald(hsrc); hv1 = ald(hsrc + 1); hv2 = ald(hsrc + 2); hv3 = ald(hsrc + 3); }
    const u64* xsrc = hb_prev + (size_t)(t & 3) * SLOT_WORDS + w0;
    u64 xv0 = 0, xv1 = 0, xv2 = 0, xv3 = 0;
    if (layer > 0) { xv0 = ald(xsrc); xv1 = ald(xsrc + 1); xv2 = ald(xsrc + 2); xv3 = ald(xsrc + 3); }

    // ---- backpressure: downstream done with step t-4 (its x = our h(t-4)) ----
    if (chk) {
      const u32 wt = (u32)(t - 3);
      while ((int)((u32)(cv >> 32) - wt) < 0) cv = ald(cw);
    }
    // ---- own-layer h(t-1): want tag t ----
    if (t > 0) {
      const u32 wt = (u32)t;
      while ((u32)(hv0 >> 32) != wt) hv0 = ald(hsrc);
      while ((u32)(hv1 >> 32) != wt) hv1 = ald(hsrc + 1);
      while ((u32)(hv2 >> 32) != wt) hv2 = ald(hsrc + 2);
      while ((u32)(hv3 >> 32) != wt) hv3 = ald(hsrc + 3);
      uint4 pw; pw.x = (u32)hv0; pw.y = (u32)hv1; pw.z = (u32)hv2; pw.w = (u32)hv3;
      *(uint4*)&h_lds[saddr] = pw;
    }
    // ---- prev-layer h(t) = x_t: want tag t+1 ----
    if (layer > 0) {
      const u32 wt = (u32)(t + 1);
      while ((u32)(xv0 >> 32) != wt) xv0 = ald(xsrc);
      while ((u32)(xv1 >> 32) != wt) xv1 = ald(xsrc + 1);
      while ((u32)(xv2 >> 32) != wt) xv2 = ald(xsrc + 2);
      while ((u32)(xv3 >> 32) != wt) xv3 = ald(xsrc + 3);
      uint4 pw; pw.x = (u32)xv0; pw.y = (u32)xv1; pw.z = (u32)xv2; pw.w = (u32)xv3;
      *(uint4*)&x_lds[saddr] = pw;
    }
    __syncthreads();

    // ---- gate MFMAs ----
    if (is_hh) {
      f32x4 a0 = {0.f, 0.f, 0.f, 0.f}, a1 = a0, a2 = a0, a3 = a0;
      if (t > 0) {
        const int rb = l15 * 256, rx = l15 << 2;
#pragma unroll
        for (int kb = 0; kb < 16; ++kb) {
          s16x8 a = *(const s16x8*)&h_lds[rb + ((kb * 16 + quad * 4) ^ rx)];
          if ((kb & 3) == 0)      a0 = __builtin_amdgcn_mfma_f32_16x16x32_bf16(a, wfrag[kb], a0, 0, 0, 0);
          else if ((kb & 3) == 1) a1 = __builtin_amdgcn_mfma_f32_16x16x32_bf16(a, wfrag[kb], a1, 0, 0, 0);
          else if ((kb & 3) == 2) a2 = __builtin_amdgcn_mfma_f32_16x16x32_bf16(a, wfrag[kb], a2, 0, 0, 0);
          else                    a3 = __builtin_amdgcn_mfma_f32_16x16x32_bf16(a, wfrag[kb], a3, 0, 0, 0);
        }
      }
      const int uc = half * 16 + l15;
#pragma unroll
      for (int r = 0; r < 4; ++r)
        gh_c[gate * 512 + (quad * 4 + r) * 32 + uc] = (a0[r] + a1[r]) + (a2[r] + a3[r]);
    } else if (do_ih) {
      f32x4 a0 = {0.f, 0.f, 0.f, 0.f}, a1 = a0, a2 = a0, a3 = a0;
      const int rb = l15 * 256, rx = l15 << 2;
#pragma unroll
      for (int kb = 0; kb < 16; ++kb) {
        s16x8 a = *(const s16x8*)&x_lds[rb + ((kb * 16 + quad * 4) ^ rx)];
        if ((kb & 3) == 0)      a0 = __builtin_amdgcn_mfma_f32_16x16x32_bf16(a, wfrag[kb], a0, 0, 0, 0);
        else if ((kb & 3) == 1) a1 = __builtin_amdgcn_mfma_f32_16x16x32_bf16(a, wfrag[kb], a1, 0, 0, 0);
        else if ((kb & 3) == 2) a2 = __builtin_amdgcn_mfma_f32_16x16x32_bf16(a, wfrag[kb], a2, 0, 0, 0);
        else                    a3 = __builtin_amdgcn_mfma_f32_16x16x32_bf16(a, wfrag[kb], a3, 0, 0, 0);
      }
      const int uc = half * 16 + l15;
#pragma unroll
      for (int r = 0; r < 4; ++r)
        gx_c[gate * 512 + (quad * 4 + r) * 32 + uc] = (a0[r] + a1[r]) + (a2[r] + a3[r]);
    }
    __syncthreads();

    // ---- combine (waves 12-15) ----
    if (is_c) {
      float hs[2];
#pragma unroll
      for (int p = 0; p < 2; ++p) {
        const int ci = ci0 + p * 256;
        const int cu = ci & 31, cb = ci >> 5;
        const int u = u0 + cu, gb = g * 16 + cb;
        float cr, cz, cn;
        if (layer == 0) {
          cr = pgx[p][0]; cz = pgx[p][1]; cn = pgx[p][2];
          if (t + 1 < TT) {
#pragma unroll
            for (int gs = 0; gs < 3; ++gs)
              pgx[p][gs] = ldgx(&gx0[(size_t)((t + 1) * NB + gb) * G3 + gs * 512 + u]);
          }
        } else {
          cr = gx_c[ci]; cz = gx_c[512 + ci]; cn = gx_c[1024 + ci];
        }
        const float ghr = gh_c[ci], ghz = gh_c[512 + ci], ghn = gh_c[1024 + ci];
        const float xr = cr + bih[p][0] + ghr + bhh[p][0];
        const float xz = cz + bih[p][1] + ghz + bhh[p][1];
        const float rr = 1.f / (1.f + __expf(-xr));
        const float zz = 1.f / (1.f + __expf(-xz));
        const float pre = cn + bih[p][2] + rr * (ghn + bhh[p][2]);
        const float ax = fabsf(pre);
        const float e = __expf(-2.f * ax);
        const float nn = copysignf((1.f - e) / (1.f + e), pre);
        const float h = (1.f - zz) * nn + zz * hprev[p];
        hprev[p] = h; hs[p] = h;
        if (layer == 2) out[((size_t)gb * TT + t) * 512 + u] = (t < slen[p]) ? h : 0.f;
      }
      // tagged broadcast of h(t) into ring slot t&3
      u64* dst = hb_own + (size_t)(t & 3) * SLOT_WORDS;
      const u64 tg = ((u64)(u32)(t + 1)) << 32;
#pragma unroll
      for (int p = 0; p < 2; ++p) {
        const float other = __shfl_xor(hs[p], 1);
        if (!(lane & 1)) {
          const int ci = ci0 + p * 256;
          const int cb = ci >> 5;
          const int u = u0 + (ci & 31);
          __hip_atomic_store(dst + cb * 256 + (u >> 1), (u64)pk2(hs[p], other) | tg,
                             __ATOMIC_RELAXED, __HIP_MEMORY_SCOPE_AGENT);
        }
      }
    }
  }
}

extern "C" void kernel_launch(void* const* d_in, const int* in_sizes, int n_in,
                              void* d_out, int out_size, void* d_ws, size_t ws_size,
                              hipStream_t stream) {
  (void)in_sizes; (void)n_in; (void)out_size;
  const float* z     = (const float*)d_in[0];
  const int*   seq   = (const int*)d_in[1];
  const float* chord = (const float*)d_in[2];
  const float* fc_w  = (const float*)d_in[3];
  const float* fc_b  = (const float*)d_in[4];
  GruP P;
  const float* w_ih0 = (const float*)d_in[5];
  P.w_ih[0] = w_ih0;                       // unused in-kernel (gx0 precomputed)
  P.w_hh[0] = (const float*)d_in[6];  P.b_ih[0] = (const float*)d_in[7];  P.b_hh[0] = (const float*)d_in[8];
  P.w_ih[1] = (const float*)d_in[9];  P.w_hh[1] = (const float*)d_in[10]; P.b_ih[1] = (const float*)d_in[11]; P.b_hh[1] = (const float*)d_in[12];
  P.w_ih[2] = (const float*)d_in[13]; P.w_hh[2] = (const float*)d_in[14]; P.b_ih[2] = (const float*)d_in[15]; P.b_hh[2] = (const float*)d_in[16];

  char* w = (char*)d_ws;
  size_t off = 0;
  auto alloc = [&](size_t bytes) -> void* {
    void* p = w + off;
    off = (off + bytes + 255) & ~(size_t)255;
    return p;
  };
  u64*   hbc = (u64*)alloc((size_t)6 * HB_WORDS * 8);   // 768 KB tagged h rings
  float* hfc = (float*)alloc((size_t)NB * HIDDEN * 4);
  short* x0  = (short*)alloc((size_t)TT * NB * HIDDEN * 2);
  short* w0b = (short*)alloc((size_t)G3 * HIDDEN * 2);
  size_t fixed = off;
  bool gx_f32 = (fixed + (size_t)TT * NB * G3 * 4) <= ws_size;
  void* gx = alloc(gx_f32 ? (size_t)TT * NB * G3 * 4 : (size_t)TT * NB * G3 * 2);

  clr_kernel<<<(6 * HB_WORDS) / 256, 256, 0, stream>>>(hbc);
  fc_kernel<<<128, 256, 0, stream>>>(z, fc_w, fc_b, hfc);
  x0_kernel<<<TT * NB, 256, 0, stream>>>(hfc, chord, x0);
  cvt_kernel<<<(G3 * HIDDEN / 4 + 255) / 256, 256, 0, stream>>>(w_ih0, w0b, G3 * HIDDEN / 4);

  dim3 gg(G3 / 128, TT * NB / 128);
  if (gx_f32) {
    float* gxf = (float*)gx;
    gemm_bt<float><<<gg, 256, 0, stream>>>(x0, w0b, gxf, TT * NB, G3, HIDDEN);
    gru3<float><<<96, 1024, 0, stream>>>(P, gxf, hbc, seq, (float*)d_out);
  } else {
    short* gxb = (short*)gx;
    gemm_bt<short><<<gg, 256, 0, stream>>>(x0, w0b, gxb, TT * NB, G3, HIDDEN);
    gru3<short><<<96, 1024, 0, stream>>>(P, gxb, hbc, seq, (float*)d_out);
  }
}